// Round 10
// baseline (810.263 us; speedup 1.0000x reference)
//
#include <hip/hip_runtime.h>
#include <hip/hip_fp16.h>

#define KDIM 1024
#define DDIM 64
#define SPAT 32768
#define NVEC 65536
#define DSP  (DDIM * SPAT)          // 2097152
#define MARGIN 6.0e-4f              // >= 4*eps(hi-only fp16 approx vs numpy-f32), worst case
#define ZPAD 65
#define QCAP 2816

typedef _Float16 half8 __attribute__((ext_vector_type(8)));
typedef float floatx4 __attribute__((ext_vector_type(4)));

__device__ __forceinline__ float opaque(float x) { asm volatile("" : "+v"(x)); return x; }

// Bitwise replica of np.add.reduce pairwise base case over fl(x[d]^2), d=0..63 (R3-proven)
__device__ __forceinline__ float np_sumsq64(const float* x) {
    float r8[8];
#pragma unroll
    for (int j = 0; j < 8; ++j) r8[j] = opaque(x[1 + j] * x[1 + j]);
#pragma unroll
    for (int i = 8; i < 56; i += 8) {
#pragma unroll
        for (int j = 0; j < 8; ++j) r8[j] += opaque(x[1 + i + j] * x[1 + i + j]);
    }
    float res = ((r8[0] + r8[1]) + (r8[2] + r8[3])) + ((r8[4] + r8[5]) + (r8[6] + r8[7]));
#pragma unroll
    for (int m = 57; m < 64; ++m) res += opaque(x[m] * x[m]);
    return opaque(x[0] * x[0]) + res;
}

// Bit-exact numpy-f32 distance, packed (distbits<<32)|k. dist ~ 64 > 0 -> monotonic bits.
__device__ __forceinline__ unsigned long long exact_score(
    const float* zr, float snr, const float* __restrict__ e2_,
    const float* __restrict__ h_, int k)
{
    const float* ep = e2_ + (size_t)k * DDIM;
    float acc = 0.f;
#pragma unroll
    for (int d = 0; d < DDIM; ++d)
        acc = fmaf(ep[d], zr[d], acc);    // sgemm: sequential f32 FMA from 0, ascending d
    float tt   = snr + h_[k];             // fl(sn + h)
    float dist = tt - acc;                // fl(t - 2 z.e)
    return ((unsigned long long)__float_as_uint(dist) << 32) | (unsigned int)k;
}

// K1: h = np-f32 ||e||^2, e2 = 2e (exact), eh = fp16(e*1024) hi plane
__global__ void vq_prep_e(const float* __restrict__ emb, float* __restrict__ e2,
                          float* __restrict__ h, __half* __restrict__ eh) {
    int k = blockIdx.x * blockDim.x + threadIdx.x;
    if (k >= KDIM) return;
    float e[DDIM];
#pragma unroll
    for (int d = 0; d < DDIM; ++d) {
        e[d] = emb[k * DDIM + d];
        e2[k * DDIM + d] = e[d] + e[d];
    }
    h[k] = np_sumsq64(e);
#pragma unroll
    for (int j = 0; j < 8; ++j) {
        half8 vh;
#pragma unroll
        for (int u = 0; u < 8; ++u)
            vh[u] = (_Float16)(e[8 * j + u] * 1024.0f);
        ((half8*)(eh + (size_t)k * DDIM))[j] = vh;
    }
}

// K2: single MFMA pass with running-threshold candidate push -> exact rescore -> epilogue
__global__ __launch_bounds__(256, 6) void vq_mfma_kernel(
    const float* __restrict__ z, const float* __restrict__ emb,
    const __half* __restrict__ eh_, const float* __restrict__ h_,
    const float* __restrict__ e2_, float* __restrict__ out,
    float* __restrict__ loss, float* __restrict__ idxf)
{
    __shared__ float zrow[64 * ZPAD];            // 16.6 KB
    __shared__ float lds_sn[64];
    __shared__ int   qcnt;
    __shared__ unsigned short     qk[QCAP];      // 5.5 KB
    __shared__ unsigned char      qn[QCAP];      // 2.75 KB
    __shared__ unsigned long long rbest[64];     // 0.5 KB

    const int tid = threadIdx.x, l = tid & 63, w = tid >> 6;
    const int nbase = blockIdx.x * 64;
    const int b = nbase >> 15, s0 = nbase & (SPAT - 1);
    const int col16 = l & 15, g16 = l >> 4;
    const float* zbase = z + (size_t)b * DSP + s0;

    if (tid == 0) qcnt = 0;
    if (tid < 64) rbest[tid] = ~0ull;

    // stage 64 z-rows: wave w loads d in [w*16, w*16+16), lane = row (coalesced 256B)
    {
        const int dbase = w * 16;
#pragma unroll
        for (int j = 0; j < 16; ++j)
            zrow[l * ZPAD + dbase + j] = zbase[(size_t)(dbase + j) * SPAT + l];
    }
    __syncthreads();

    if (tid < 64) lds_sn[tid] = np_sumsq64(&zrow[tid * ZPAD]);

    // resident Z hi fragments
    half8 zf[4][2];
#pragma unroll
    for (int nc = 0; nc < 4; ++nc) {
        const int r = nc * 16 + col16;
#pragma unroll
        for (int kp = 0; kp < 2; ++kp) {
            const int d0 = g16 * 8 + kp * 32;
            half8 vh;
#pragma unroll
            for (int u = 0; u < 8; ++u)
                vh[u] = (_Float16)zrow[r * ZPAD + d0 + u];
            zf[nc][kp] = vh;
        }
    }

    // ---- single pass: MFMA scan, push candidates within running-min + MARGIN ----
    // score-space: dist = h_k - 2*dot (sn dropped: constant per column, ordering unchanged)
    float runmin[4];
#pragma unroll
    for (int nc = 0; nc < 4; ++nc) runmin[nc] = 3.0e38f;

    const int myk0 = w * 256;
    {
        size_t eoff = (size_t)(myk0 + col16) * DDIM + g16 * 8;
        half8 ef0 = *(const half8*)(eh_ + eoff);
        half8 ef1 = *(const half8*)(eh_ + eoff + 32);
        floatx4 hv = *(const floatx4*)(h_ + myk0 + g16 * 4);
        for (int t = 0; t < 16; ++t) {
            half8 cf0 = ef0, cf1 = ef1; floatx4 chv = hv;
            if (t < 15) {
                const size_t e2off = (size_t)(myk0 + (t + 1) * 16 + col16) * DDIM + g16 * 8;
                ef0 = *(const half8*)(eh_ + e2off);
                ef1 = *(const half8*)(eh_ + e2off + 32);
                hv  = *(const floatx4*)(h_ + myk0 + (t + 1) * 16 + g16 * 4);
            }
            const int rbase = myk0 + t * 16 + g16 * 4;
#pragma unroll
            for (int nc = 0; nc < 4; ++nc) {
                floatx4 acc = {0.f, 0.f, 0.f, 0.f};
                acc = __builtin_amdgcn_mfma_f32_16x16x32_f16(cf0, zf[nc][0], acc, 0, 0, 0);
                acc = __builtin_amdgcn_mfma_f32_16x16x32_f16(cf1, zf[nc][1], acc, 0, 0, 0);
#pragma unroll
                for (int j = 0; j < 4; ++j) {
                    float dist = fmaf(-0.001953125f, acc[j], chv[j]);  // h - 2^-9*acc
                    if (dist <= runmin[nc] + MARGIN) {
                        const int row = nc * 16 + col16;
                        int p = atomicAdd(&qcnt, 1);
                        if (p < QCAP) {
                            qk[p] = (unsigned short)(rbase + j);
                            qn[p] = (unsigned char)row;
                        } else {
                            // overflow-safe: rescore inline (astronomically rare)
                            float snr = np_sumsq64(&zrow[row * ZPAD]);
                            atomicMin(&rbest[row],
                                      exact_score(&zrow[row * ZPAD], snr, e2_, h_, rbase + j));
                        }
                    }
                    runmin[nc] = fminf(runmin[nc], dist);
                }
            }
        }
    }
    __syncthreads();

    // ---- exact rescore of all candidates (bit-exact numpy-f32), atomicMin per row ----
    const int qlen = min(qcnt, QCAP);
    for (int i = tid; i < qlen; i += 256) {
        const int k = qk[i], r = qn[i];
        atomicMin(&rbest[r], exact_score(&zrow[r * ZPAD], lds_sn[r], e2_, h_, k));
    }
    __syncthreads();

    // ---- epilogue: idx, z_q gather, loss ----
    if (tid < 64) {
        const int I1 = (int)(rbest[tid] & 0xffffffffu);
        const int n = nbase + tid;
        idxf[n] = (float)I1;

        const float* e = emb + (size_t)I1 * DDIM;
        float* op = out + (size_t)b * DSP + s0 + tid;
        float lsum = 0.f;
#pragma unroll
        for (int d = 0; d < DDIM; ++d) {
            float qv = e[d];
            op[(size_t)d * SPAT] = qv;
            float df = qv - zrow[tid * ZPAD + d];
            lsum = fmaf(df, df, lsum);
        }
#pragma unroll
        for (int off = 32; off > 0; off >>= 1)
            lsum += __shfl_down(lsum, off, 64);
        if (tid == 0)
            atomicAdd(loss, lsum * (1.25f / 4194304.0f));  // (beta+1)*mean
    }
}

extern "C" void kernel_launch(void* const* d_in, const int* in_sizes, int n_in,
                              void* d_out, int out_size, void* d_ws, size_t ws_size,
                              hipStream_t stream) {
    const float* z   = (const float*)d_in[0];   // [2, 64, 32, 32, 32]
    const float* emb = (const float*)d_in[1];   // [1024, 64]
    float* out  = (float*)d_out;                // z_q (4194304) | loss (1) | indices (65536)
    float* loss = out + 4194304;
    float* idxf = out + 4194305;

    float* h_  = (float*)d_ws;                  // [1024]
    float* e2_ = h_ + KDIM;                     // [1024*64]
    __half* eh_ = (__half*)(e2_ + KDIM * DDIM); // [1024*64] halves

    hipMemsetAsync(loss, 0, sizeof(float), stream);
    vq_prep_e<<<KDIM / 256, 256, 0, stream>>>(emb, e2_, h_, eh_);
    vq_mfma_kernel<<<NVEC / 64, 256, 0, stream>>>(z, emb, eh_, h_, e2_, out, loss, idxf);
}

// Round 11
// 71.561 us; speedup vs baseline: 11.3227x; 11.3227x over previous
//
#include <hip/hip_runtime.h>
#include <hip/hip_fp16.h>

#define KDIM 1024
#define DDIM 64
#define SPAT 32768
#define NVEC 65536
#define DSP  (DDIM * SPAT)          // 2097152
#define MARGIN 5.0e-4f              // >= bound(hi-only fp16 approx vs numpy-f32 score) ~1.8e-4
#define ZPAD 65
#define QCAP 1536

typedef _Float16 half8 __attribute__((ext_vector_type(8)));
typedef float floatx4 __attribute__((ext_vector_type(4)));

__device__ __forceinline__ float opaque(float x) { asm volatile("" : "+v"(x)); return x; }

// sortable-uint transform for SIGNED floats (monotone): compare/atomicMin-safe
__device__ __forceinline__ unsigned int f2s(float x) {
    unsigned int u = __float_as_uint(x);
    return u ^ ((u >> 31) ? 0xffffffffu : 0x80000000u);
}
__device__ __forceinline__ float s2f(unsigned int u) {
    unsigned int v = u ^ ((u & 0x80000000u) ? 0x80000000u : 0xffffffffu);
    return __uint_as_float(v);
}

// Bitwise replica of np.add.reduce pairwise base case over fl(x[d]^2), d=0..63 (R3-proven)
__device__ __forceinline__ float np_sumsq64(const float* x) {
    float r8[8];
#pragma unroll
    for (int j = 0; j < 8; ++j) r8[j] = opaque(x[1 + j] * x[1 + j]);
#pragma unroll
    for (int i = 8; i < 56; i += 8) {
#pragma unroll
        for (int j = 0; j < 8; ++j) r8[j] += opaque(x[1 + i + j] * x[1 + i + j]);
    }
    float res = ((r8[0] + r8[1]) + (r8[2] + r8[3])) + ((r8[4] + r8[5]) + (r8[6] + r8[7]));
#pragma unroll
    for (int m = 57; m < 64; ++m) res += opaque(x[m] * x[m]);
    return opaque(x[0] * x[0]) + res;
}

// Bit-exact numpy-f32 distance, packed (distbits<<32)|k. Exact dist ~ sn (>0) -> monotone bits.
__device__ __forceinline__ unsigned long long exact_score(
    const float* zr, float snr, const float* __restrict__ e2_,
    const float* __restrict__ h_, int k)
{
    const float* ep = e2_ + (size_t)k * DDIM;
    float acc = 0.f;
#pragma unroll
    for (int d = 0; d < DDIM; ++d)
        acc = fmaf(ep[d], zr[d], acc);    // sgemm: sequential f32 FMA from 0, ascending d
    float tt   = snr + h_[k];             // fl(sn + h)
    float dist = tt - acc;                // fl(t - 2 z.e)
    return ((unsigned long long)__float_as_uint(dist) << 32) | (unsigned int)k;
}

// K1: LDS-staged prep. 64 k-rows/block: h = np-f32 ||e||^2, e2 = 2e, eh = fp16(e*1024)
__global__ void vq_prep_e(const float* __restrict__ emb, float* __restrict__ e2,
                          float* __restrict__ h, __half* __restrict__ eh) {
    __shared__ float L[64 * ZPAD];
    const int tid = threadIdx.x;
    const int kbase = blockIdx.x * 64;
    const float* src = emb + (size_t)kbase * DDIM;
#pragma unroll
    for (int i = 0; i < 16; ++i) {
        int g = i * 256 + tid;
        L[(g >> 6) * ZPAD + (g & 63)] = src[g];
    }
    __syncthreads();
#pragma unroll
    for (int i = 0; i < 16; ++i) {
        int g = i * 256 + tid;
        float v = L[(g >> 6) * ZPAD + (g & 63)];
        e2[(size_t)kbase * DDIM + g] = v + v;
        eh[(size_t)kbase * DDIM + g] = (__half)(_Float16)(v * 1024.0f);
    }
    if (tid < 64) h[kbase + tid] = np_sumsq64(&L[tid * ZPAD]);
}

// K2: two-pass MFMA (approx min -> candidate queue) + bit-exact rescore + epilogue
__global__ __launch_bounds__(256, 4) void vq_mfma_kernel(
    const float* __restrict__ z, const float* __restrict__ emb,
    const __half* __restrict__ eh_, const float* __restrict__ h_,
    const float* __restrict__ e2_, float* __restrict__ out,
    float* __restrict__ loss, float* __restrict__ idxf)
{
    __shared__ float zrow[64 * ZPAD];            // 16.6 KB
    __shared__ float lds_sn[64];
    __shared__ unsigned int m1bits[64];          // sortable-uint row min
    __shared__ int qcnt;
    __shared__ unsigned short     qk[QCAP];      // 3 KB
    __shared__ unsigned char      qn[QCAP];      // 1.5 KB
    __shared__ unsigned long long rbest[64];     // 0.5 KB

    const int tid = threadIdx.x, l = tid & 63, w = tid >> 6;
    const int nbase = blockIdx.x * 64;
    const int b = nbase >> 15, s0 = nbase & (SPAT - 1);
    const int col16 = l & 15, g16 = l >> 4;
    const float* zbase = z + (size_t)b * DSP + s0;

    if (tid == 0) qcnt = 0;
    if (tid < 64) { rbest[tid] = ~0ull; m1bits[tid] = 0xffffffffu; }

    // stage 64 z-rows: wave w loads d in [w*16, w*16+16), lane = row (coalesced 256B)
    {
        const int dbase = w * 16;
#pragma unroll
        for (int j = 0; j < 16; ++j)
            zrow[l * ZPAD + dbase + j] = zbase[(size_t)(dbase + j) * SPAT + l];
    }
    __syncthreads();

    if (tid < 64) lds_sn[tid] = np_sumsq64(&zrow[tid * ZPAD]);

    // resident Z hi fragments
    half8 zf[4][2];
#pragma unroll
    for (int nc = 0; nc < 4; ++nc) {
        const int r = nc * 16 + col16;
#pragma unroll
        for (int kp = 0; kp < 2; ++kp) {
            const int d0 = g16 * 8 + kp * 32;
            half8 vh;
#pragma unroll
            for (int u = 0; u < 8; ++u)
                vh[u] = (_Float16)zrow[r * ZPAD + d0 + u];
            zf[nc][kp] = vh;
        }
    }

    const int myk0 = w * 256;
    half8 f0[3], f1[3]; floatx4 fh[3];
    // score-space: s = h_k - 2^-9*acc (sn dropped: per-row constant, ordering unchanged)
#define LOADT(slot, t) { \
        const size_t o_ = (size_t)(myk0 + (t) * 16 + col16) * DDIM + g16 * 8; \
        f0[slot] = *(const half8*)(eh_ + o_); \
        f1[slot] = *(const half8*)(eh_ + o_ + 32); \
        fh[slot] = *(const floatx4*)(h_ + myk0 + (t) * 16 + g16 * 4); }

    // ---- phase 1: approx row min (2-deep prefetch) ----
    float m1[4];
#pragma unroll
    for (int nc = 0; nc < 4; ++nc) m1[nc] = 3.0e38f;
    LOADT(0, 0) LOADT(1, 1)
#pragma unroll
    for (int t = 0; t < 16; ++t) {
        const int cs = t % 3;
        if (t < 14) LOADT((t + 2) % 3, t + 2)
#pragma unroll
        for (int nc = 0; nc < 4; ++nc) {
            floatx4 acc = {0.f, 0.f, 0.f, 0.f};
            acc = __builtin_amdgcn_mfma_f32_16x16x32_f16(f0[cs], zf[nc][0], acc, 0, 0, 0);
            acc = __builtin_amdgcn_mfma_f32_16x16x32_f16(f1[cs], zf[nc][1], acc, 0, 0, 0);
#pragma unroll
            for (int j = 0; j < 4; ++j)
                m1[nc] = fminf(m1[nc], fmaf(-0.001953125f, acc[j], fh[cs][j]));
        }
    }
#pragma unroll
    for (int nc = 0; nc < 4; ++nc)
        atomicMin(&m1bits[nc * 16 + col16], f2s(m1[nc]));
    __syncthreads();

    float thr[4];
#pragma unroll
    for (int nc = 0; nc < 4; ++nc) thr[nc] = s2f(m1bits[nc * 16 + col16]) + MARGIN;

    // ---- phase 2: re-scan, push candidates within MARGIN of row min ----
    LOADT(0, 0) LOADT(1, 1)
#pragma unroll
    for (int t = 0; t < 16; ++t) {
        const int cs = t % 3;
        if (t < 14) LOADT((t + 2) % 3, t + 2)
        const int rbase = myk0 + t * 16 + g16 * 4;
#pragma unroll
        for (int nc = 0; nc < 4; ++nc) {
            floatx4 acc = {0.f, 0.f, 0.f, 0.f};
            acc = __builtin_amdgcn_mfma_f32_16x16x32_f16(f0[cs], zf[nc][0], acc, 0, 0, 0);
            acc = __builtin_amdgcn_mfma_f32_16x16x32_f16(f1[cs], zf[nc][1], acc, 0, 0, 0);
#pragma unroll
            for (int j = 0; j < 4; ++j) {
                float dist = fmaf(-0.001953125f, acc[j], fh[cs][j]);
                if (dist <= thr[nc]) {
                    int p = atomicAdd(&qcnt, 1);
                    if (p < QCAP) {
                        qk[p] = (unsigned short)(rbase + j);
                        qn[p] = (unsigned char)(nc * 16 + col16);
                    }
                }
            }
        }
    }
#undef LOADT
    __syncthreads();

    // ---- phase 3: bit-exact numpy-f32 rescore of candidates, atomicMin per row ----
    const int qlen = min(qcnt, QCAP);
    for (int i = tid; i < qlen; i += 256) {
        const int r = qn[i];
        atomicMin(&rbest[r], exact_score(&zrow[r * ZPAD], lds_sn[r], e2_, h_, qk[i]));
    }
    __syncthreads();

    if (qcnt > QCAP) {   // cold correctness fallback: full exact scan (never in practice)
        const int row = tid & 63, kq = tid >> 6;
        for (int k = kq * 256; k < kq * 256 + 256; ++k)
            atomicMin(&rbest[row], exact_score(&zrow[row * ZPAD], lds_sn[row], e2_, h_, k));
        __syncthreads();
    }

    // ---- epilogue: idx, z_q gather, loss ----
    if (tid < 64) {
        const int I1 = (int)(rbest[tid] & 0xffffffffu);
        const int n = nbase + tid;
        idxf[n] = (float)I1;

        const float* e = emb + (size_t)I1 * DDIM;
        float* op = out + (size_t)b * DSP + s0 + tid;
        float lsum = 0.f;
#pragma unroll
        for (int d = 0; d < DDIM; ++d) {
            float qv = e[d];
            op[(size_t)d * SPAT] = qv;
            float df = qv - zrow[tid * ZPAD + d];
            lsum = fmaf(df, df, lsum);
        }
#pragma unroll
        for (int off = 32; off > 0; off >>= 1)
            lsum += __shfl_down(lsum, off, 64);
        if (tid == 0)
            atomicAdd(loss, lsum * (1.25f / 4194304.0f));  // (beta+1)*mean
    }
}

extern "C" void kernel_launch(void* const* d_in, const int* in_sizes, int n_in,
                              void* d_out, int out_size, void* d_ws, size_t ws_size,
                              hipStream_t stream) {
    const float* z   = (const float*)d_in[0];   // [2, 64, 32, 32, 32]
    const float* emb = (const float*)d_in[1];   // [1024, 64]
    float* out  = (float*)d_out;                // z_q (4194304) | loss (1) | indices (65536)
    float* loss = out + 4194304;
    float* idxf = out + 4194305;

    float* h_  = (float*)d_ws;                  // [1024]
    float* e2_ = h_ + KDIM;                     // [1024*64]
    __half* eh_ = (__half*)(e2_ + KDIM * DDIM); // [1024*64] halves

    hipMemsetAsync(loss, 0, sizeof(float), stream);
    vq_prep_e<<<KDIM / 64, 256, 0, stream>>>(emb, e2_, h_, eh_);
    vq_mfma_kernel<<<NVEC / 64, 256, 0, stream>>>(z, emb, eh_, h_, e2_, out, loss, idxf);
}